// Round 14
// baseline (46.873 us; speedup 1.0000x reference)
//
#include <hip/hip_runtime.h>

typedef float v2f __attribute__((ext_vector_type(2)));

#define WPB 4   // waves per block
#define NE  4   // elements per wave in prep kernel

__device__ __forceinline__ float xorf(float v, int sb) {
  return __int_as_float(__float_as_int(v) ^ sb);
}

// ---- VOP3P packed fp32 helpers (R3-verified) ----------------------------
__device__ __forceinline__ void pkfma_ip(v2f a, v2f b, v2f& acc) {
  asm("v_pk_fma_f32 %0, %1, %2, %0" : "+v"(acc) : "v"(a), "v"(b));
}
__device__ __forceinline__ v2f pkmul_bl(v2f c, v2f v) {
  v2f r; asm("v_pk_mul_f32 %0, %1, %2 op_sel:[0,0] op_sel_hi:[0,1]"
             : "=v"(r) : "v"(c), "v"(v)); return r;
}
__device__ __forceinline__ void pkfma_bl(v2f c, v2f v, v2f& acc) {
  asm("v_pk_fma_f32 %0, %1, %2, %0 op_sel:[0,0,0] op_sel_hi:[0,1,1]"
      : "+v"(acc) : "v"(c), "v"(v));
}
__device__ __forceinline__ void pkfma_bl_n(v2f c, v2f v, v2f& acc) {
  asm("v_pk_fma_f32 %0, %1, %2, %0 op_sel:[0,0,0] op_sel_hi:[0,1,1] neg_lo:[1,0,0] neg_hi:[1,0,0]"
      : "+v"(acc) : "v"(c), "v"(v));
}
__device__ __forceinline__ void pkfma_bh_i(v2f c, v2f v, v2f& acc) {
  asm("v_pk_fma_f32 %0, %1, %2, %0 op_sel:[1,1,0] op_sel_hi:[1,0,1] neg_lo:[1,0,0]"
      : "+v"(acc) : "v"(c), "v"(v));
}
__device__ __forceinline__ void pkfma_bh_mi(v2f c, v2f v, v2f& acc) {
  asm("v_pk_fma_f32 %0, %1, %2, %0 op_sel:[1,1,0] op_sel_hi:[1,0,1] neg_hi:[1,0,0]"
      : "+v"(acc) : "v"(c), "v"(v));
}
__device__ __forceinline__ v2f cmul(v2f a, v2f b) {
  v2f r = pkmul_bl(a, b);
  pkfma_bh_i(a, b, r);
  return r;
}

// ---- cross-lane xor exchange (R6-verified prims) ------------------------
template<int M>
__device__ __forceinline__ float xch(float v, int a32) {
  if constexpr (M == 32)
    return __int_as_float(__builtin_amdgcn_ds_bpermute(a32, __float_as_int(v)));
  else if constexpr (M == 16 || M == 4)
    return __int_as_float(__builtin_amdgcn_ds_swizzle(__float_as_int(v), (M << 10) | 0x1f));
  else if constexpr (M == 8) {
    int i = __float_as_int(v);
    return __int_as_float(__builtin_amdgcn_update_dpp(i, i, 0x128, 0xF, 0xF, false));
  } else if constexpr (M == 2) {
    int i = __float_as_int(v);
    return __int_as_float(__builtin_amdgcn_update_dpp(i, i, 0x4E, 0xF, 0xF, false));
  } else {
    int i = __float_as_int(v);
    return __int_as_float(__builtin_amdgcn_update_dpp(i, i, 0xB1, 0xF, 0xF, false));
  }
}
template<int M>
__device__ __forceinline__ v2f xch2(v2f v, int a32) {
  v2f r; r.x = xch<M>(v.x, a32); r.y = xch<M>(v.y, a32); return r;
}
__device__ __forceinline__ v2f bperm2(int addr, v2f v) {
  v2f r;
  r.x = __int_as_float(__builtin_amdgcn_ds_bpermute(addr, __float_as_int(v.x)));
  r.y = __int_as_float(__builtin_amdgcn_ds_bpermute(addr, __float_as_int(v.y)));
  return r;
}

// ---- gate cores (R7-verified) -------------------------------------------
__device__ __forceinline__ void gpair(v2f& a, v2f& b, v2f P1, v2f P2) {
  v2f na = pkmul_bl(P1, a);
  pkfma_bh_i(P1, a, na);
  pkfma_bl(P2, b, na);
  pkfma_bh_i(P2, b, na);
  v2f nb = pkmul_bl(P1, b);
  pkfma_bh_mi(P1, b, nb);
  pkfma_bl_n(P2, a, nb);
  pkfma_bh_i(P2, a, nb);
  a = na; b = nb;
}
__device__ __forceinline__ v2f glane(v2f a, v2f p, v2f P1, v2f P2) {
  v2f t = pkmul_bl(P1, a);
  pkfma_bh_i(P1, a, t);
  pkfma_bl(P2, p, t);
  pkfma_bh_i(P2, p, t);
  return t;
}

// wire W on one element's 4 named state regs (signs pre-applied for W>=2)
template<int W>
__device__ __forceinline__ void gate_elem(v2f& S0, v2f& S1, v2f& S2, v2f& S3,
                                          v2f P1, v2f P2, int a32) {
  if constexpr (W == 0)      { gpair(S0, S2, P1, P2); gpair(S1, S3, P1, P2); }
  else if constexpr (W == 1) { gpair(S0, S1, P1, P2); gpair(S2, S3, P1, P2); }
  else {
    constexpr int M = 1 << (7 - W);
    v2f p0 = xch2<M>(S0, a32), p1 = xch2<M>(S1, a32),
        p2 = xch2<M>(S2, a32), p3 = xch2<M>(S3, a32);
    S0 = glane(S0, p0, P1, P2); S1 = glane(S1, p1, P1, P2);
    S2 = glane(S2, p2, P1, P2); S3 = glane(S3, p3, P1, P2);
  }
}

// product-state build (init + layer-0 Rot folded) into named regs
__device__ __forceinline__ void build_state(v2f& S0, v2f& S1, v2f& S2, v2f& S3,
                                            const float4* csW, int lane) {
  v2f g2, g3, g4, g5, g6, g7;
  #define BG(q, dst) { float4 c = csW[q]; \
    v2f P1 = (v2f){c.x, c.y}; v2f nc2 = (v2f){-c.z, c.w}; \
    dst = (((lane >> (7 - (q))) & 1) != 0) ? nc2 : P1; }
  BG(2, g2) BG(3, g3) BG(4, g4) BG(5, g5) BG(6, g6) BG(7, g7)
  #undef BG
  v2f common = cmul(cmul(cmul(g2, g3), cmul(g4, g5)), cmul(g6, g7));
  float4 c0 = csW[0], c1 = csW[1];
  v2f P10 = (v2f){c0.x, c0.y}, m0 = (v2f){-c0.z, c0.w};
  v2f P11 = (v2f){c1.x, c1.y}, m1 = (v2f){-c1.z, c1.w};
  S0 = cmul(cmul(P10, P11), common);
  S1 = cmul(cmul(P10, m1 ), common);
  S2 = cmul(cmul(m0 , P11), common);
  S3 = cmul(cmul(m0 , m1 ), common);
}

__device__ __forceinline__ void cnot_ring(v2f& S0, v2f& S1, v2f& S2, v2f& S3,
                                          int addrA, int addrB, int lane) {
  { v2f t = S2; S2 = S3; S3 = t; }
  S0 = bperm2(addrA, S0); S2 = bperm2(addrA, S2);
  S1 = bperm2(addrB, S1); S3 = bperm2(addrB, S3);
  bool c0 = (lane & 1) != 0;
  v2f t0 = S0, t1 = S1;
  S0 = c0 ? S2 : S0; S2 = c0 ? t0 : S2;
  S1 = c0 ? S3 : S1; S3 = c0 ? t1 : S3;
}

__device__ __forceinline__ float fast_tanh(float x) {
  float e = __expf(2.f * x);
  return 1.f - 2.f * __builtin_amdgcn_rcpf(e + 1.f);
}
__device__ __forceinline__ v2f vlo(float4 v) { return (v2f){v.x, v.y}; }
__device__ __forceinline__ v2f vhi(float4 v) { return (v2f){v.z, v.w}; }

__global__ void prep_rot_kernel(const float* __restrict__ qw, float* __restrict__ U) {
  int t = threadIdx.x;
  if (t < 24) {
    float phi = qw[t*3+0], theta = qw[t*3+1], omega = qw[t*3+2];
    float st, ct; sincosf(0.5f*theta, &st, &ct);
    float sa, ca; sincosf(0.5f*(phi+omega), &sa, &ca);
    float sd, cd; sincosf(0.5f*(phi-omega), &sd, &cd);
    float4 o; o.x = ct*ca; o.y = -ct*sa; o.z = -st*cd; o.w = -st*sd;
    ((float4*)U)[t] = o;
  }
}

// ====== Kernel A: MLP + fused per-wire gate coefficients -> global csWg ===
__global__ __launch_bounds__(64*WPB) void prep_kernel(
    const float* __restrict__ x,  const float* __restrict__ W1, const float* __restrict__ b1,
    const float* __restrict__ W2, const float* __restrict__ b2,
    const float* __restrict__ W3, const float* __restrict__ b3,
    const float* __restrict__ Urot, float4* __restrict__ csWg, int B4)
{
  __shared__ float h1s[WPB][NE][64];
  __shared__ float h2s[WPB][NE][32];
  __shared__ v2f   cs [WPB][NE][16];

  const int lane = threadIdx.x & 63;
  const int wv   = threadIdx.x >> 6;
  int bw = blockIdx.x * WPB + wv;
  if (bw >= B4) bw = B4 - 1;
  bw = __builtin_amdgcn_readfirstlane(bw);
  const int e0 = NE * bw;
  const v2f* Ug2 = (const v2f*)Urot;

  // layer 1: 80 -> 64 for 4 elements
  {
    const float4* wr = (const float4*)(W1 + lane * 80);
    float bv = b1[lane];
    v2f a0A = (v2f){bv,0.f}, a1A = (v2f){0.f,0.f};
    v2f a0B = a0A, a1B = a1A, a0C = a0A, a1C = a1A, a0D = a0A, a1D = a1A;
    #pragma unroll
    for (int k = 0; k < 20; ++k) {
      float4 wk = wr[k];
      #define L1E(E, e) { \
        float4 xk = ((const float4*)(x + (size_t)(e0 + (e)) * 80))[k]; \
        pkfma_ip(vlo(xk), vlo(wk), a0##E); pkfma_ip(vhi(xk), vhi(wk), a1##E); }
      L1E(A,0) L1E(B,1) L1E(C,2) L1E(D,3)
      #undef L1E
    }
    h1s[wv][0][lane] = fast_tanh((a0A.x + a0A.y) + (a1A.x + a1A.y));
    h1s[wv][1][lane] = fast_tanh((a0B.x + a0B.y) + (a1B.x + a1B.y));
    h1s[wv][2][lane] = fast_tanh((a0C.x + a0C.y) + (a1C.x + a1C.y));
    h1s[wv][3][lane] = fast_tanh((a0D.x + a0D.y) + (a1D.x + a1D.y));
  }
  __threadfence_block();

  // layer 2: 64 -> 32; 2 elems per lane
  {
    const int ep = lane >> 5, row = lane & 31;
    const float4* wr = (const float4*)(W2 + row * 64);
    const float4* hvA = (const float4*)(&h1s[wv][2*ep+0][0]);
    const float4* hvB = (const float4*)(&h1s[wv][2*ep+1][0]);
    v2f aA0 = (v2f){b2[row], 0.f}, aA1 = (v2f){0.f, 0.f};
    v2f aB0 = aA0, aB1 = aA1;
    #pragma unroll
    for (int k = 0; k < 16; ++k) {
      float4 wk = wr[k], hA = hvA[k], hB = hvB[k];
      pkfma_ip(vlo(hA), vlo(wk), aA0); pkfma_ip(vhi(hA), vhi(wk), aA1);
      pkfma_ip(vlo(hB), vlo(wk), aB0); pkfma_ip(vhi(hB), vhi(wk), aB1);
    }
    h2s[wv][2*ep+0][row] = fast_tanh((aA0.x + aA0.y) + (aA1.x + aA1.y));
    h2s[wv][2*ep+1][row] = fast_tanh((aB0.x + aB0.y) + (aB1.x + aB1.y));
  }
  __threadfence_block();

  // layer 3: 32 -> 16 angles; all 64 lanes
  {
    const int e = lane >> 4, row = lane & 15;
    const float4* hv = (const float4*)(&h2s[wv][e][0]);
    const float4* wr = (const float4*)(W3 + row * 32);
    v2f ac0 = (v2f){b3[row], 0.f}, ac1 = (v2f){0.f, 0.f};
    #pragma unroll
    for (int k = 0; k < 8; ++k) {
      float4 hk = hv[k], wk = wr[k];
      pkfma_ip(vlo(hk), vlo(wk), ac0);
      pkfma_ip(vhi(hk), vhi(wk), ac1);
    }
    float sh, ch; __sincosf(0.5f * ((ac0.x + ac0.y) + (ac1.x + ac1.y)), &sh, &ch);
    cs[wv][e][row] = (v2f){ch, sh};
  }
  __threadfence_block();

  // combine W_i = Rot_l0_i . (RZ_i . RY_i) -> global csWg[(e0+e)*8 + k]
  if (lane < 32) {
    const int e = lane >> 3, k = lane & 7;
    v2f yy = cs[wv][e][k], zz = cs[wv][e][k + 8];
    v2f u1 = (v2f){  yy.x * zz.x, -yy.x * zz.y };
    v2f u2 = (v2f){ -yy.y * zz.x,  yy.y * zz.y };
    v2f cu1 = (v2f){ u1.x, -u1.y };
    v2f cu2 = (v2f){ u2.x, -u2.y };
    v2f r1 = Ug2[2 * k], r2 = Ug2[2 * k + 1];
    v2f P1c = cmul(r1, u1);
    pkfma_bl_n(r2, cu2, P1c);
    pkfma_bh_mi(r2, cu2, P1c);
    v2f P2c = cmul(r1, u2);
    pkfma_bl(r2, cu1, P2c);
    pkfma_bh_i(r2, cu1, P2c);
    csWg[(size_t)(e0 + e) * 8 + k] = make_float4(P1c.x, P1c.y, P2c.x, P2c.y);
  }
}

// ====== Kernel B: circuit + readout + projection, ONE element per wave ====
__global__ __launch_bounds__(64*WPB) void qcirc_kernel(
    const float* __restrict__ Urot, const float4* __restrict__ csWg,
    const float* __restrict__ Wp, const float* __restrict__ bp,
    float* __restrict__ out, int B)
{
  const int lane = threadIdx.x & 63;
  const int wv   = threadIdx.x >> 6;
  int e = blockIdx.x * WPB + wv;
  if (e >= B) e = B - 1;
  e = __builtin_amdgcn_readfirstlane(e);
  const v2f* Ug2 = (const v2f*)Urot;

  const int a32 = (lane ^ 32) << 2;
  const int sb[6] = { (lane&32)<<26, (lane&16)<<27, (lane&8)<<28,
                      (lane&4)<<29, (lane&2)<<30, (lane&1)<<31 };
  const int addrA = ((lane ^ (lane >> 1)) & 63) << 2;
  const int addrB = addrA ^ 128;

  v2f s0, s1, s2, s3;
  build_state(s0, s1, s2, s3, csWg + (size_t)e * 8, lane);
  cnot_ring(s0, s1, s2, s3, addrA, addrB, lane);

  #define LG(l, i) { \
    v2f P1 = Ug2[((l)*8+(i))*2], P2 = Ug2[((l)*8+(i))*2+1]; \
    if constexpr ((i) >= 2) { \
      P1.y = xorf(P1.y, sb[(i)-2]); P2.x = xorf(P2.x, sb[(i)-2]); } \
    gate_elem<i>(s0, s1, s2, s3, P1, P2, a32); }
  LG(1,0) LG(1,1) LG(1,2) LG(1,3) LG(1,4) LG(1,5) LG(1,6) LG(1,7)
  cnot_ring(s0, s1, s2, s3, addrA, addrB, lane);
  LG(2,0) LG(2,1) LG(2,2) LG(2,3) LG(2,4) LG(2,5) LG(2,6) LG(2,7)
  #undef LG

  // readout (ring 2 folded as parity signs) — scalar, R3/R6-verified algebra
  float p0 = s0.x*s0.x + s0.y*s0.y;
  float p1 = s1.x*s1.x + s1.y*s1.y;
  float p2 = s2.x*s2.x + s2.y*s2.y;
  float p3 = s3.x*s3.x + s3.y*s3.y;
  float E = (p0 + p3) - (p1 + p2);
  float F = (p0 + p2) - (p1 + p3);
  float Fv = xorf(F, (__popc(lane) & 1) << 31);
  float Sm = E, d1, d2, d3, d4, d5, d6;
  { float p = xch<32>(Sm, a32); d1 = xorf(Sm - p, sb[0]); Sm += p; }
  { float p = xch<16>(Sm, a32); Sm += p;
    float q = xch<16>(d1, a32); d2 = xorf(d1 - q, sb[1]); d1 += q; }
  { float p = xch<8>(Sm, a32); Sm += p;
    float q = xch<8>(d1, a32); d1 += q;
    float r = xch<8>(d2, a32); d3 = xorf(d2 - r, sb[2]); d2 += r; }
  { float p = xch<4>(Sm, a32); Sm += p;
    float q = xch<4>(d1, a32); d1 += q;
    float r = xch<4>(d2, a32); d2 += r;
    float t = xch<4>(d3, a32); d4 = xorf(d3 - t, sb[3]); d3 += t; }
  { float p = xch<2>(Sm, a32); Sm += p;
    float q = xch<2>(d1, a32); d1 += q;
    float r = xch<2>(d2, a32); d2 += r;
    float t = xch<2>(d3, a32); d3 += t;
    float w = xch<2>(d4, a32); d5 = xorf(d4 - w, sb[4]); d4 += w; }
  { float p = xch<1>(Sm, a32); Sm += p;
    float q = xch<1>(d1, a32); d1 += q;
    float r = xch<1>(d2, a32); d2 += r;
    float t = xch<1>(d3, a32); d3 += t;
    float w = xch<1>(d4, a32); d4 += w;
    float v = xch<1>(d5, a32); d6 = xorf(d5 - v, sb[5]); d5 += v; }
  Fv += xch<32>(Fv, a32); Fv += xch<16>(Fv, a32); Fv += xch<8>(Fv, a32);
  Fv += xch<4>(Fv, a32);  Fv += xch<2>(Fv, a32);  Fv += xch<1>(Fv, a32);
  const float z0 = Fv, z1 = Sm, z2 = d1, z3 = d2, z4 = d3, z5 = d4, z6 = d5, z7 = d6;

  // projection: rows 2*lane, 2*lane+1 of Wp (128x8)
  const int r0 = 2 * lane;
  const float4* wp = (const float4*)(Wp + r0 * 8);
  float4 w0v = wp[0], w1v = wp[1], w2v = wp[2], w3v = wp[3];
  float2 bpv = ((const float2*)bp)[lane];
  float o0 = bpv.x + z0*w0v.x + z1*w0v.y + z2*w0v.z + z3*w0v.w
                   + z4*w1v.x + z5*w1v.y + z6*w1v.z + z7*w1v.w;
  float o1 = bpv.y + z0*w2v.x + z1*w2v.y + z2*w2v.z + z3*w2v.w
                   + z4*w3v.x + z5*w3v.y + z6*w3v.z + z7*w3v.w;
  ((float2*)(out + (size_t)e * 128))[lane] = make_float2(o0, o1);
}

extern "C" void kernel_launch(void* const* d_in, const int* in_sizes, int n_in,
                              void* d_out, int out_size, void* d_ws, size_t ws_size,
                              hipStream_t stream) {
  const float* x  = (const float*)d_in[0];
  const float* W1 = (const float*)d_in[1];
  const float* b1 = (const float*)d_in[2];
  const float* W2 = (const float*)d_in[3];
  const float* b2 = (const float*)d_in[4];
  const float* W3 = (const float*)d_in[5];
  const float* b3 = (const float*)d_in[6];
  const float* qw = (const float*)d_in[7];
  const float* Wp = (const float*)d_in[8];
  const float* bp = (const float*)d_in[9];
  float* out = (float*)d_out;
  float* Urot = (float*)d_ws;                                   // 384 B
  float4* csWg = (float4*)((char*)d_ws + 1024);                 // B*8*16 B = 2 MB

  const int B = in_sizes[0] / 80;
  const int B4 = B / NE;
  prep_rot_kernel<<<1, 64, 0, stream>>>(qw, Urot);
  prep_kernel<<<(B4 + WPB - 1) / WPB, 64 * WPB, 0, stream>>>(
      x, W1, b1, W2, b2, W3, b3, Urot, csWg, B4);
  qcirc_kernel<<<(B + WPB - 1) / WPB, 64 * WPB, 0, stream>>>(
      Urot, csWg, Wp, bp, out, B);
}

// Round 16
// 42.015 us; speedup vs baseline: 1.1156x; 1.1156x over previous
//
#include <hip/hip_runtime.h>

typedef float v2f __attribute__((ext_vector_type(2)));

#define WPB 4   // waves per block
#define NE  4   // batch elements per wave

#define SE(E,N) s##E##N   // paste helper: SE(B,3).x avoids '3.x' pp-number bug

__device__ __forceinline__ float xorf(float v, int sb) {
  return __int_as_float(__float_as_int(v) ^ sb);
}
__device__ __forceinline__ v2f xor2(v2f v, int sb) {
  return (v2f){xorf(v.x, sb), xorf(v.y, sb)};
}

// ---- VOP3P packed fp32 helpers; accumulating forms in-place (+v) --------
__device__ __forceinline__ void pkfma_ip(v2f a, v2f b, v2f& acc) {
  asm("v_pk_fma_f32 %0, %1, %2, %0" : "+v"(acc) : "v"(a), "v"(b));
}
__device__ __forceinline__ v2f pkmul_bl(v2f c, v2f v) {
  v2f r; asm("v_pk_mul_f32 %0, %1, %2 op_sel:[0,0] op_sel_hi:[0,1]"
             : "=v"(r) : "v"(c), "v"(v)); return r;
}
__device__ __forceinline__ void pkfma_bl(v2f c, v2f v, v2f& acc) {
  asm("v_pk_fma_f32 %0, %1, %2, %0 op_sel:[0,0,0] op_sel_hi:[0,1,1]"
      : "+v"(acc) : "v"(c), "v"(v));
}
__device__ __forceinline__ void pkfma_bl_n(v2f c, v2f v, v2f& acc) {
  asm("v_pk_fma_f32 %0, %1, %2, %0 op_sel:[0,0,0] op_sel_hi:[0,1,1] neg_lo:[1,0,0] neg_hi:[1,0,0]"
      : "+v"(acc) : "v"(c), "v"(v));
}
__device__ __forceinline__ void pkfma_bh_i(v2f c, v2f v, v2f& acc) {
  asm("v_pk_fma_f32 %0, %1, %2, %0 op_sel:[1,1,0] op_sel_hi:[1,0,1] neg_lo:[1,0,0]"
      : "+v"(acc) : "v"(c), "v"(v));
}
__device__ __forceinline__ void pkfma_bh_mi(v2f c, v2f v, v2f& acc) {
  asm("v_pk_fma_f32 %0, %1, %2, %0 op_sel:[1,1,0] op_sel_hi:[1,0,1] neg_hi:[1,0,0]"
      : "+v"(acc) : "v"(c), "v"(v));
}
__device__ __forceinline__ v2f cmul(v2f a, v2f b) {
  v2f r = pkmul_bl(a, b);
  pkfma_bh_i(a, b, r);
  return r;
}

// ---- scalar DPP exchange for masks 8,2,1 (VALU pipe) ---------------------
template<int M>
__device__ __forceinline__ float xch_dpp(float v) {
  int i = __float_as_int(v);
  if constexpr (M == 8)
    return __int_as_float(__builtin_amdgcn_update_dpp(i, i, 0x128, 0xF, 0xF, false));
  else if constexpr (M == 2)
    return __int_as_float(__builtin_amdgcn_update_dpp(i, i, 0x4E, 0xF, 0xF, false));
  else
    return __int_as_float(__builtin_amdgcn_update_dpp(i, i, 0xB1, 0xF, 0xF, false));
}
template<int M>
__device__ __forceinline__ v2f xch2_dpp(v2f v) {
  v2f r; r.x = xch_dpp<M>(v.x); r.y = xch_dpp<M>(v.y); return r;
}
// scalar DS exchange (readout cascade only)
template<int M>
__device__ __forceinline__ float xch(float v, int a32) {
  if constexpr (M == 32)
    return __int_as_float(__builtin_amdgcn_ds_bpermute(a32, __float_as_int(v)));
  else if constexpr (M == 16 || M == 4)
    return __int_as_float(__builtin_amdgcn_ds_swizzle(__float_as_int(v), (M << 10) | 0x1f));
  else
    return xch_dpp<M>(v);
}
template<int M>
__device__ __forceinline__ v2f xch2(v2f v, int a32) {
  v2f r; r.x = xch<M>(v.x, a32); r.y = xch<M>(v.y, a32); return r;
}

// ---- gate cores (R7-verified) -------------------------------------------
__device__ __forceinline__ void gpair(v2f& a, v2f& b, v2f P1, v2f P2) {
  v2f na = pkmul_bl(P1, a);
  pkfma_bh_i(P1, a, na);
  pkfma_bl(P2, b, na);
  pkfma_bh_i(P2, b, na);
  v2f nb = pkmul_bl(P1, b);
  pkfma_bh_mi(P1, b, nb);
  pkfma_bl_n(P2, a, nb);
  pkfma_bh_i(P2, a, nb);
  a = na; b = nb;
}
__device__ __forceinline__ v2f glane(v2f a, v2f p, v2f P1, v2f P2) {
  v2f t = pkmul_bl(P1, a);
  pkfma_bh_i(P1, a, t);
  pkfma_bl(P2, p, t);
  pkfma_bh_i(P2, p, t);
  return t;
}

// product-state build (init + layer-0 Rot folded) into named regs
__device__ __forceinline__ void build_state(v2f& S0, v2f& S1, v2f& S2, v2f& S3,
                                            const float4* csW, int lane) {
  v2f g2, g3, g4, g5, g6, g7;
  #define BG(q, dst) { float4 c = csW[q]; \
    v2f P1 = (v2f){c.x, c.y}; v2f nc2 = (v2f){-c.z, c.w}; \
    dst = (((lane >> (7 - (q))) & 1) != 0) ? nc2 : P1; }
  BG(2, g2) BG(3, g3) BG(4, g4) BG(5, g5) BG(6, g6) BG(7, g7)
  #undef BG
  v2f common = cmul(cmul(cmul(g2, g3), cmul(g4, g5)), cmul(g6, g7));
  float4 c0 = csW[0], c1 = csW[1];
  v2f P10 = (v2f){c0.x, c0.y}, m0 = (v2f){-c0.z, c0.w};
  v2f P11 = (v2f){c1.x, c1.y}, m1 = (v2f){-c1.z, c1.w};
  S0 = cmul(cmul(P10, P11), common);
  S1 = cmul(cmul(P10, m1 ), common);
  S2 = cmul(cmul(m0 , P11), common);
  S3 = cmul(cmul(m0 , m1 ), common);
}

__device__ __forceinline__ float fast_tanh(float x) {
  float e = __expf(2.f * x);
  return 1.f - 2.f * __builtin_amdgcn_rcpf(e + 1.f);
}
__device__ __forceinline__ v2f vlo(float4 v) { return (v2f){v.x, v.y}; }
__device__ __forceinline__ v2f vhi(float4 v) { return (v2f){v.z, v.w}; }

__global__ void prep_rot_kernel(const float* __restrict__ qw, float* __restrict__ U) {
  int t = threadIdx.x;
  if (t < 24) {
    float phi = qw[t*3+0], theta = qw[t*3+1], omega = qw[t*3+2];
    float st, ct; sincosf(0.5f*theta, &st, &ct);
    float sa, ca; sincosf(0.5f*(phi+omega), &sa, &ca);
    float sd, cd; sincosf(0.5f*(phi-omega), &sd, &cd);
    float4 o; o.x = ct*ca; o.y = -ct*sa; o.z = -st*cd; o.w = -st*sd;
    ((float4*)U)[t] = o;
  }
}

__global__ __launch_bounds__(64*WPB, 4) void qblock_kernel(
    const float* __restrict__ x,  const float* __restrict__ W1, const float* __restrict__ b1,
    const float* __restrict__ W2, const float* __restrict__ b2,
    const float* __restrict__ W3, const float* __restrict__ b3,
    const float* __restrict__ Urot, const float* __restrict__ Wp, const float* __restrict__ bp,
    float* __restrict__ out, int B4)
{
  __shared__ float  h1s[WPB][NE][64];
  __shared__ float  h2s[WPB][NE][32];
  __shared__ v2f    cs [WPB][NE][16];
  __shared__ float4 csW[WPB][NE][8];

  const int lane = threadIdx.x & 63;
  const int wv   = threadIdx.x >> 6;
  int bw = blockIdx.x * WPB + wv;
  if (bw >= B4) bw = B4 - 1;
  bw = __builtin_amdgcn_readfirstlane(bw);
  const int e0 = NE * bw;
  const v2f* Ug2 = (const v2f*)Urot;

  // ---- MLP layer 1: 80 -> 64 for 4 elements ----
  {
    const float4* wr = (const float4*)(W1 + lane * 80);
    float bv = b1[lane];
    v2f a0A = (v2f){bv,0.f}, a1A = (v2f){0.f,0.f};
    v2f a0B = a0A, a1B = a1A, a0C = a0A, a1C = a1A, a0D = a0A, a1D = a1A;
    #pragma unroll
    for (int k = 0; k < 20; ++k) {
      float4 wk = wr[k];
      #define L1E(E, e) { \
        float4 xk = ((const float4*)(x + (size_t)(e0 + (e)) * 80))[k]; \
        pkfma_ip(vlo(xk), vlo(wk), a0##E); pkfma_ip(vhi(xk), vhi(wk), a1##E); }
      L1E(A,0) L1E(B,1) L1E(C,2) L1E(D,3)
      #undef L1E
    }
    h1s[wv][0][lane] = fast_tanh((a0A.x + a0A.y) + (a1A.x + a1A.y));
    h1s[wv][1][lane] = fast_tanh((a0B.x + a0B.y) + (a1B.x + a1B.y));
    h1s[wv][2][lane] = fast_tanh((a0C.x + a0C.y) + (a1C.x + a1C.y));
    h1s[wv][3][lane] = fast_tanh((a0D.x + a0D.y) + (a1D.x + a1D.y));
  }
  __threadfence_block();

  // ---- layer 2: 64 -> 32; 2 elems per lane ----
  {
    const int ep = lane >> 5, row = lane & 31;
    const float4* wr = (const float4*)(W2 + row * 64);
    const float4* hvA = (const float4*)(&h1s[wv][2*ep+0][0]);
    const float4* hvB = (const float4*)(&h1s[wv][2*ep+1][0]);
    v2f aA0 = (v2f){b2[row], 0.f}, aA1 = (v2f){0.f, 0.f};
    v2f aB0 = aA0, aB1 = aA1;
    #pragma unroll
    for (int k = 0; k < 16; ++k) {
      float4 wk = wr[k], hA = hvA[k], hB = hvB[k];
      pkfma_ip(vlo(hA), vlo(wk), aA0); pkfma_ip(vhi(hA), vhi(wk), aA1);
      pkfma_ip(vlo(hB), vlo(wk), aB0); pkfma_ip(vhi(hB), vhi(wk), aB1);
    }
    h2s[wv][2*ep+0][row] = fast_tanh((aA0.x + aA0.y) + (aA1.x + aA1.y));
    h2s[wv][2*ep+1][row] = fast_tanh((aB0.x + aB0.y) + (aB1.x + aB1.y));
  }
  __threadfence_block();

  // ---- layer 3: 32 -> 16 angles; all 64 lanes ----
  {
    const int e = lane >> 4, row = lane & 15;
    const float4* hv = (const float4*)(&h2s[wv][e][0]);
    const float4* wr = (const float4*)(W3 + row * 32);
    v2f ac0 = (v2f){b3[row], 0.f}, ac1 = (v2f){0.f, 0.f};
    #pragma unroll
    for (int k = 0; k < 8; ++k) {
      float4 hk = hv[k], wk = wr[k];
      pkfma_ip(vlo(hk), vlo(wk), ac0);
      pkfma_ip(vhi(hk), vhi(wk), ac1);
    }
    float sh, ch; __sincosf(0.5f * ((ac0.x + ac0.y) + (ac1.x + ac1.y)), &sh, &ch);
    cs[wv][e][row] = (v2f){ch, sh};
  }
  __threadfence_block();

  // ---- combine W_i = Rot_l0_i . (RZ_i . RY_i): lane = (elem, wire) ----
  if (lane < 32) {
    const int e = lane >> 3, k = lane & 7;
    v2f yy = cs[wv][e][k], zz = cs[wv][e][k + 8];
    v2f u1 = (v2f){  yy.x * zz.x, -yy.x * zz.y };
    v2f u2 = (v2f){ -yy.y * zz.x,  yy.y * zz.y };
    v2f cu1 = (v2f){ u1.x, -u1.y };
    v2f cu2 = (v2f){ u2.x, -u2.y };
    v2f r1 = Ug2[2 * k], r2 = Ug2[2 * k + 1];
    v2f P1c = cmul(r1, u1);
    pkfma_bl_n(r2, cu2, P1c);
    pkfma_bh_mi(r2, cu2, P1c);
    v2f P2c = cmul(r1, u2);
    pkfma_bl(r2, cu1, P2c);
    pkfma_bh_i(r2, cu1, P2c);
    csW[wv][e][k] = make_float4(P1c.x, P1c.y, P2c.x, P2c.y);
  }
  __threadfence_block();

  // ---- per-lane constants ----
  const int a32 = (lane ^ 32) << 2;
  const int sb[6] = { (lane&32)<<26, (lane&16)<<27, (lane&8)<<28,
                      (lane&4)<<29, (lane&2)<<30, (lane&1)<<31 };
  const int addrA = ((lane ^ (lane >> 1)) & 63) << 2;
  const int addrB = addrA ^ 128;

  v2f sA0, sA1, sA2, sA3, sB0, sB1, sB2, sB3;
  v2f sC0, sC1, sC2, sC3, sD0, sD1, sD2, sD3;
  build_state(sA0, sA1, sA2, sA3, &csW[wv][0][0], lane);
  build_state(sB0, sB1, sB2, sB3, &csW[wv][1][0], lane);
  build_state(sC0, sC1, sC2, sC3, &csW[wv][2][0], lane);
  build_state(sD0, sD1, sD2, sD3, &csW[wv][3][0], lane);

  // batched-exchange gate for DS wires (8 ds ops in flight per element)
  #define EX8_BP(E, P1s, P2s) { \
    float pax,pay,pbx,pby,pcx,pcy,pdx,pdy; \
    asm volatile( \
      "ds_bpermute_b32 %0, %16, %8\n\t" \
      "ds_bpermute_b32 %1, %16, %9\n\t" \
      "ds_bpermute_b32 %2, %16, %10\n\t" \
      "ds_bpermute_b32 %3, %16, %11\n\t" \
      "ds_bpermute_b32 %4, %16, %12\n\t" \
      "ds_bpermute_b32 %5, %16, %13\n\t" \
      "ds_bpermute_b32 %6, %16, %14\n\t" \
      "ds_bpermute_b32 %7, %16, %15\n\t" \
      "s_waitcnt lgkmcnt(0)" \
      : "=&v"(pax), "=&v"(pay), "=&v"(pbx), "=&v"(pby), \
        "=&v"(pcx), "=&v"(pcy), "=&v"(pdx), "=&v"(pdy) \
      : "v"(SE(E,0).x), "v"(SE(E,0).y), "v"(SE(E,1).x), "v"(SE(E,1).y), \
        "v"(SE(E,2).x), "v"(SE(E,2).y), "v"(SE(E,3).x), "v"(SE(E,3).y), \
        "v"(a32)); \
    v2f p0 = (v2f){pax,pay}, p1 = (v2f){pbx,pby}, \
        p2 = (v2f){pcx,pcy}, p3 = (v2f){pdx,pdy}; \
    SE(E,0) = glane(SE(E,0), p0, P1s, P2s); \
    SE(E,1) = glane(SE(E,1), p1, P1s, P2s); \
    SE(E,2) = glane(SE(E,2), p2, P1s, P2s); \
    SE(E,3) = glane(SE(E,3), p3, P1s, P2s); }

  #define EX8_SWZ(E, IMM, P1s, P2s) { \
    float pax,pay,pbx,pby,pcx,pcy,pdx,pdy; \
    asm volatile( \
      "ds_swizzle_b32 %0, %8 offset:" IMM "\n\t" \
      "ds_swizzle_b32 %1, %9 offset:" IMM "\n\t" \
      "ds_swizzle_b32 %2, %10 offset:" IMM "\n\t" \
      "ds_swizzle_b32 %3, %11 offset:" IMM "\n\t" \
      "ds_swizzle_b32 %4, %12 offset:" IMM "\n\t" \
      "ds_swizzle_b32 %5, %13 offset:" IMM "\n\t" \
      "ds_swizzle_b32 %6, %14 offset:" IMM "\n\t" \
      "ds_swizzle_b32 %7, %15 offset:" IMM "\n\t" \
      "s_waitcnt lgkmcnt(0)" \
      : "=&v"(pax), "=&v"(pay), "=&v"(pbx), "=&v"(pby), \
        "=&v"(pcx), "=&v"(pcy), "=&v"(pdx), "=&v"(pdy) \
      : "v"(SE(E,0).x), "v"(SE(E,0).y), "v"(SE(E,1).x), "v"(SE(E,1).y), \
        "v"(SE(E,2).x), "v"(SE(E,2).y), "v"(SE(E,3).x), "v"(SE(E,3).y)); \
    v2f p0 = (v2f){pax,pay}, p1 = (v2f){pbx,pby}, \
        p2 = (v2f){pcx,pcy}, p3 = (v2f){pdx,pdy}; \
    SE(E,0) = glane(SE(E,0), p0, P1s, P2s); \
    SE(E,1) = glane(SE(E,1), p1, P1s, P2s); \
    SE(E,2) = glane(SE(E,2), p2, P1s, P2s); \
    SE(E,3) = glane(SE(E,3), p3, P1s, P2s); }

  // DPP-wire gate (masks 8,2,1): VALU pipe
  #define EXDPP(E, M, P1s, P2s) { \
    v2f p0 = xch2_dpp<M>(SE(E,0)), p1 = xch2_dpp<M>(SE(E,1)), \
        p2 = xch2_dpp<M>(SE(E,2)), p3 = xch2_dpp<M>(SE(E,3)); \
    SE(E,0) = glane(SE(E,0), p0, P1s, P2s); \
    SE(E,1) = glane(SE(E,1), p1, P1s, P2s); \
    SE(E,2) = glane(SE(E,2), p2, P1s, P2s); \
    SE(E,3) = glane(SE(E,3), p3, P1s, P2s); }

  #define SIGNS(l, i) \
    v2f P1s = Ug2[((l)*8+(i))*2], P2s = Ug2[((l)*8+(i))*2+1]; \
    P1s.y = xorf(P1s.y, sb[(i)-2]); P2s.x = xorf(P2s.x, sb[(i)-2]);

  #define LG0(l) { v2f P1 = Ug2[((l)*8+0)*2], P2 = Ug2[((l)*8+0)*2+1]; \
    gpair(sA0, sA2, P1, P2); gpair(sA1, sA3, P1, P2); \
    gpair(sB0, sB2, P1, P2); gpair(sB1, sB3, P1, P2); \
    gpair(sC0, sC2, P1, P2); gpair(sC1, sC3, P1, P2); \
    gpair(sD0, sD2, P1, P2); gpair(sD1, sD3, P1, P2); }
  #define LG1(l) { v2f P1 = Ug2[((l)*8+1)*2], P2 = Ug2[((l)*8+1)*2+1]; \
    gpair(sA0, sA1, P1, P2); gpair(sA2, sA3, P1, P2); \
    gpair(sB0, sB1, P1, P2); gpair(sB2, sB3, P1, P2); \
    gpair(sC0, sC1, P1, P2); gpair(sC2, sC3, P1, P2); \
    gpair(sD0, sD1, P1, P2); gpair(sD2, sD3, P1, P2); }
  #define LW2(l) { SIGNS(l,2) EX8_BP(A,P1s,P2s) EX8_BP(B,P1s,P2s) \
                   EX8_BP(C,P1s,P2s) EX8_BP(D,P1s,P2s) }
  #define LW3(l) { SIGNS(l,3) EX8_SWZ(A,"0x401F",P1s,P2s) EX8_SWZ(B,"0x401F",P1s,P2s) \
                   EX8_SWZ(C,"0x401F",P1s,P2s) EX8_SWZ(D,"0x401F",P1s,P2s) }
  #define LW4(l) { SIGNS(l,4) EXDPP(A,8,P1s,P2s) EXDPP(B,8,P1s,P2s) \
                   EXDPP(C,8,P1s,P2s) EXDPP(D,8,P1s,P2s) }
  #define LW5(l) { SIGNS(l,5) EX8_SWZ(A,"0x101F",P1s,P2s) EX8_SWZ(B,"0x101F",P1s,P2s) \
                   EX8_SWZ(C,"0x101F",P1s,P2s) EX8_SWZ(D,"0x101F",P1s,P2s) }
  #define LW6(l) { SIGNS(l,6) EXDPP(A,2,P1s,P2s) EXDPP(B,2,P1s,P2s) \
                   EXDPP(C,2,P1s,P2s) EXDPP(D,2,P1s,P2s) }
  #define LW7(l) { SIGNS(l,7) EXDPP(A,1,P1s,P2s) EXDPP(B,1,P1s,P2s) \
                   EXDPP(C,1,P1s,P2s) EXDPP(D,1,P1s,P2s) }

  // CNOT ring with batched bpermutes
  #define RING_E(E) { \
    { v2f t = SE(E,2); SE(E,2) = SE(E,3); SE(E,3) = t; } \
    float qax,qay,qbx,qby,qcx,qcy,qdx,qdy; \
    asm volatile( \
      "ds_bpermute_b32 %0, %16, %8\n\t" \
      "ds_bpermute_b32 %1, %16, %9\n\t" \
      "ds_bpermute_b32 %2, %17, %10\n\t" \
      "ds_bpermute_b32 %3, %17, %11\n\t" \
      "ds_bpermute_b32 %4, %16, %12\n\t" \
      "ds_bpermute_b32 %5, %16, %13\n\t" \
      "ds_bpermute_b32 %6, %17, %14\n\t" \
      "ds_bpermute_b32 %7, %17, %15\n\t" \
      "s_waitcnt lgkmcnt(0)" \
      : "=&v"(qax), "=&v"(qay), "=&v"(qbx), "=&v"(qby), \
        "=&v"(qcx), "=&v"(qcy), "=&v"(qdx), "=&v"(qdy) \
      : "v"(SE(E,0).x), "v"(SE(E,0).y), "v"(SE(E,1).x), "v"(SE(E,1).y), \
        "v"(SE(E,2).x), "v"(SE(E,2).y), "v"(SE(E,3).x), "v"(SE(E,3).y), \
        "v"(addrA), "v"(addrB)); \
    bool c0 = (lane & 1) != 0; \
    v2f q0 = (v2f){qax,qay}, q1 = (v2f){qbx,qby}, \
        q2 = (v2f){qcx,qcy}, q3 = (v2f){qdx,qdy}; \
    SE(E,0) = c0 ? q2 : q0; SE(E,2) = c0 ? q0 : q2; \
    SE(E,1) = c0 ? q3 : q1; SE(E,3) = c0 ? q1 : q3; }
  #define RING_ALL RING_E(A) RING_E(B) RING_E(C) RING_E(D)

  RING_ALL
  LG0(1) LG1(1) LW2(1) LW3(1) LW4(1) LW5(1) LW6(1) LW7(1)
  RING_ALL
  LG0(2) LG1(2) LW2(2) LW3(2) LW4(2) LW5(2) LW6(2) LW7(2)

  // ---- interleaved readout for 4 elements (pair-groups u=(A,B), w=(C,D)) ----
  v2f zu0,zu1,zu2,zu3,zu4,zu5,zu6,zu7;
  v2f zw0,zw1,zw2,zw3,zw4,zw5,zw6,zw7;
  {
    v2f pu0 = (v2f){fmaf(sA0.x,sA0.x,sA0.y*sA0.y), fmaf(sB0.x,sB0.x,sB0.y*sB0.y)};
    v2f pu1 = (v2f){fmaf(sA1.x,sA1.x,sA1.y*sA1.y), fmaf(sB1.x,sB1.x,sB1.y*sB1.y)};
    v2f pu2 = (v2f){fmaf(sA2.x,sA2.x,sA2.y*sA2.y), fmaf(sB2.x,sB2.x,sB2.y*sB2.y)};
    v2f pu3 = (v2f){fmaf(sA3.x,sA3.x,sA3.y*sA3.y), fmaf(sB3.x,sB3.x,sB3.y*sB3.y)};
    v2f pw0 = (v2f){fmaf(sC0.x,sC0.x,sC0.y*sC0.y), fmaf(sD0.x,sD0.x,sD0.y*sD0.y)};
    v2f pw1 = (v2f){fmaf(sC1.x,sC1.x,sC1.y*sC1.y), fmaf(sD1.x,sD1.x,sD1.y*sD1.y)};
    v2f pw2 = (v2f){fmaf(sC2.x,sC2.x,sC2.y*sC2.y), fmaf(sD2.x,sD2.x,sD2.y*sD2.y)};
    v2f pw3 = (v2f){fmaf(sC3.x,sC3.x,sC3.y*sC3.y), fmaf(sD3.x,sD3.x,sD3.y*sD3.y)};
    v2f Eu = (pu0 + pu3) - (pu1 + pu2), Fu = (pu0 + pu2) - (pu1 + pu3);
    v2f Ew = (pw0 + pw3) - (pw1 + pw2), Fw = (pw0 + pw2) - (pw1 + pw3);
    const int pl = (__popc(lane) & 1) << 31;
    v2f Fvu = xor2(Fu, pl), Fvw = xor2(Fw, pl);
    v2f Smu = Eu, Smw = Ew;
    v2f d1u, d2u, d3u, d4u, d5u, d6u, d1w, d2w, d3w, d4w, d5w, d6w;
    { v2f pu = xch2<32>(Smu, a32); v2f pw = xch2<32>(Smw, a32);
      d1u = xor2(Smu - pu, sb[0]); Smu += pu;
      d1w = xor2(Smw - pw, sb[0]); Smw += pw; }
    { v2f pu = xch2<16>(Smu, a32), qu = xch2<16>(d1u, a32);
      v2f pw = xch2<16>(Smw, a32), qw = xch2<16>(d1w, a32);
      Smu += pu; d2u = xor2(d1u - qu, sb[1]); d1u += qu;
      Smw += pw; d2w = xor2(d1w - qw, sb[1]); d1w += qw; }
    { v2f pu = xch2<8>(Smu, a32), qu = xch2<8>(d1u, a32), ru = xch2<8>(d2u, a32);
      v2f pw = xch2<8>(Smw, a32), qw = xch2<8>(d1w, a32), rw = xch2<8>(d2w, a32);
      Smu += pu; d1u += qu; d3u = xor2(d2u - ru, sb[2]); d2u += ru;
      Smw += pw; d1w += qw; d3w = xor2(d2w - rw, sb[2]); d2w += rw; }
    { v2f pu = xch2<4>(Smu, a32), qu = xch2<4>(d1u, a32),
          ru = xch2<4>(d2u, a32), tu = xch2<4>(d3u, a32);
      v2f pw = xch2<4>(Smw, a32), qw = xch2<4>(d1w, a32),
          rw = xch2<4>(d2w, a32), tw = xch2<4>(d3w, a32);
      Smu += pu; d1u += qu; d2u += ru; d4u = xor2(d3u - tu, sb[3]); d3u += tu;
      Smw += pw; d1w += qw; d2w += rw; d4w = xor2(d3w - tw, sb[3]); d3w += tw; }
    { v2f pu = xch2<2>(Smu, a32), qu = xch2<2>(d1u, a32), ru = xch2<2>(d2u, a32),
          tu = xch2<2>(d3u, a32), wu = xch2<2>(d4u, a32);
      v2f pw = xch2<2>(Smw, a32), qw = xch2<2>(d1w, a32), rw = xch2<2>(d2w, a32),
          tw = xch2<2>(d3w, a32), ww = xch2<2>(d4w, a32);
      Smu += pu; d1u += qu; d2u += ru; d3u += tu;
      d5u = xor2(d4u - wu, sb[4]); d4u += wu;
      Smw += pw; d1w += qw; d2w += rw; d3w += tw;
      d5w = xor2(d4w - ww, sb[4]); d4w += ww; }
    { v2f pu = xch2<1>(Smu, a32), qu = xch2<1>(d1u, a32), ru = xch2<1>(d2u, a32),
          tu = xch2<1>(d3u, a32), wu = xch2<1>(d4u, a32), vu = xch2<1>(d5u, a32);
      v2f pw = xch2<1>(Smw, a32), qw = xch2<1>(d1w, a32), rw = xch2<1>(d2w, a32),
          tw = xch2<1>(d3w, a32), ww = xch2<1>(d4w, a32), vw = xch2<1>(d5w, a32);
      Smu += pu; d1u += qu; d2u += ru; d3u += tu; d4u += wu;
      d6u = xor2(d5u - vu, sb[5]); d5u += vu;
      Smw += pw; d1w += qw; d2w += rw; d3w += tw; d4w += ww;
      d6w = xor2(d5w - vw, sb[5]); d5w += vw; }
    Fvu += xch2<32>(Fvu, a32); Fvw += xch2<32>(Fvw, a32);
    Fvu += xch2<16>(Fvu, a32); Fvw += xch2<16>(Fvw, a32);
    Fvu += xch2<8>(Fvu, a32);  Fvw += xch2<8>(Fvw, a32);
    Fvu += xch2<4>(Fvu, a32);  Fvw += xch2<4>(Fvw, a32);
    Fvu += xch2<2>(Fvu, a32);  Fvw += xch2<2>(Fvw, a32);
    Fvu += xch2<1>(Fvu, a32);  Fvw += xch2<1>(Fvw, a32);
    zu0 = Fvu; zu1 = Smu; zu2 = d1u; zu3 = d2u;
    zu4 = d3u; zu5 = d4u; zu6 = d5u; zu7 = d6u;
    zw0 = Fvw; zw1 = Smw; zw2 = d1w; zw3 = d2w;
    zw4 = d3w; zw5 = d4w; zw6 = d5w; zw7 = d6w;
  }

  // ---- packed projection + stores ----
  const int r0 = 2 * lane;
  const float4* wp = (const float4*)(Wp + r0 * 8);
  float4 w0v = wp[0], w1v = wp[1], w2v = wp[2], w3v = wp[3];
  float2 bpv = ((const float2*)bp)[lane];
  #define PROJ_STORE(P, eA, eB) { \
    v2f o0 = (v2f){bpv.x, bpv.x}; \
    v2f o1 = (v2f){bpv.y, bpv.y}; \
    o0 += z##P##0*w0v.x + z##P##1*w0v.y + z##P##2*w0v.z + z##P##3*w0v.w \
        + z##P##4*w1v.x + z##P##5*w1v.y + z##P##6*w1v.z + z##P##7*w1v.w; \
    o1 += z##P##0*w2v.x + z##P##1*w2v.y + z##P##2*w2v.z + z##P##3*w2v.w \
        + z##P##4*w3v.x + z##P##5*w3v.y + z##P##6*w3v.z + z##P##7*w3v.w; \
    ((float2*)(out + (size_t)(e0 + (eA)) * 128))[lane] = make_float2(o0.x, o1.x); \
    ((float2*)(out + (size_t)(e0 + (eB)) * 128))[lane] = make_float2(o0.y, o1.y); }
  PROJ_STORE(u, 0, 1)
  PROJ_STORE(w, 2, 3)
  #undef PROJ_STORE
}

extern "C" void kernel_launch(void* const* d_in, const int* in_sizes, int n_in,
                              void* d_out, int out_size, void* d_ws, size_t ws_size,
                              hipStream_t stream) {
  const float* x  = (const float*)d_in[0];
  const float* W1 = (const float*)d_in[1];
  const float* b1 = (const float*)d_in[2];
  const float* W2 = (const float*)d_in[3];
  const float* b2 = (const float*)d_in[4];
  const float* W3 = (const float*)d_in[5];
  const float* b3 = (const float*)d_in[6];
  const float* qw = (const float*)d_in[7];
  const float* Wp = (const float*)d_in[8];
  const float* bp = (const float*)d_in[9];
  float* out = (float*)d_out;
  float* Urot = (float*)d_ws;

  const int B = in_sizes[0] / 80;
  const int B4 = B / NE;
  prep_rot_kernel<<<1, 64, 0, stream>>>(qw, Urot);
  const int grid = (B4 + WPB - 1) / WPB;
  qblock_kernel<<<grid, 64 * WPB, 0, stream>>>(x, W1, b1, W2, b2, W3, b3,
                                               Urot, Wp, bp, out, B4);
}